// Round 3
// baseline (488.246 us; speedup 1.0000x reference)
//
#include <hip/hip_runtime.h>

typedef unsigned short u16;
typedef float f32x16 __attribute__((ext_vector_type(16)));
typedef short bf16x8 __attribute__((ext_vector_type(8)));

#define DHW 131072            // 32*64*64
// packed-weight offsets in ushort units inside d_ws
#define OFF_WQ 0
#define OFF_WK 16384
#define OFF_WV 32768
#define OFF_WO 49152
#define OFF_W1 65536
#define OFF_W2 131072

__device__ __forceinline__ float b2f(u16 u){ union{unsigned i; float f;} x; x.i=((unsigned)u)<<16; return x.f; }
__device__ __forceinline__ u16 f2b(float f){ union{float f; unsigned u;} x; x.f=f; unsigned r=x.u+0x7fffu+((x.u>>16)&1u); return (u16)(r>>16); }
__device__ __forceinline__ unsigned pk2bf(float lo, float hi){
  unsigned r; asm("v_cvt_pk_bf16_f32 %0, %1, %2" : "=v"(r) : "v"(lo), "v"(hi)); return r;
}
__device__ __forceinline__ float lo2f(unsigned u){ union{unsigned i; float f;} x; x.i=u<<16; return x.f; }
__device__ __forceinline__ float hi2f(unsigned u){ union{unsigned i; float f;} x; x.i=u&0xffff0000u; return x.f; }
// swizzled u16 offset of channel c (0..127) in row tok of a [64][128] bf16 buffer (16B cells, cell ^= tok&7)
__device__ __forceinline__ int cofs(int tok, int c){ return (tok<<7) + ((((c>>3) ^ (tok&7)))<<3) + (c&7); }

// ---------------- weight pack: fp32 [K][N] -> bf16 frags for mfma_32x32x16 (A-operand of W^T) ----------------
// frag (ct,ks): lane l holds W[ks*16 + (l>>5)*8 + j][ct*32 + (l&31)], j=0..7 (16B/lane); frag id f = ct*(K/16)+ks
__global__ void pack_w(const float* __restrict__ Wq, const float* __restrict__ Wk,
                       const float* __restrict__ Wv, const float* __restrict__ Wo,
                       const float* __restrict__ W1, const float* __restrict__ W2,
                       u16* __restrict__ ws){
  int tid = blockIdx.x*256 + threadIdx.x;       // 0..24575
  const float* src; int dst, K, N, fb;
  if      (tid <  2048){ src=Wq; dst=OFF_WQ; K=128; N=128; fb=tid;       }
  else if (tid <  4096){ src=Wk; dst=OFF_WK; K=128; N=128; fb=tid-2048;  }
  else if (tid <  6144){ src=Wv; dst=OFF_WV; K=128; N=128; fb=tid-4096;  }
  else if (tid <  8192){ src=Wo; dst=OFF_WO; K=128; N=128; fb=tid-6144;  }
  else if (tid < 16384){ src=W1; dst=OFF_W1; K=128; N=512; fb=tid-8192;  }
  else                 { src=W2; dst=OFF_W2; K=512; N=128; fb=tid-16384; }
  int l = fb & 63, f = fb >> 6;
  int ksc = K >> 4;
  int ct = f / ksc, ks = f - ct*ksc;
  int k0 = ks*16 + ((l>>5)<<3);
  int col = ct*32 + (l&31);
  union { uint4 v; u16 u[8]; } pk;
  #pragma unroll
  for (int j=0;j<8;j++) pk.u[j] = f2b(src[(k0+j)*N + col]);
  *reinterpret_cast<uint4*>(ws + dst + f*512 + l*8) = pk.v;
}

// ---------------- transposed-D micro-GEMM, 32x32x16: D[ch][tok] = (X @ W)^T ----------------
// wave tile: 2 ch-tiles (cb, cb+1) x 1 tok-tile. acc[cw]: f32x16, row(ch) = (reg&3)+8*(reg>>2)+4*hi, col(tok)=l&31.
__device__ __forceinline__ f32x16 z16(){ f32x16 z; 
  #pragma unroll
  for(int i=0;i<16;i++) z[i]=0.f; return z; }

__device__ __forceinline__ void mm32(const u16* __restrict__ act, const u16* __restrict__ wf,
                                     int cb, int ksc, int ks0, int tok, int hi, int l,
                                     f32x16 (&acc)[2]){
  #pragma unroll
  for (int kst=0; kst<8; ++kst){
    int g = kst*2 + hi;
    bf16x8 a  = *(const bf16x8*)(act + (tok<<7) + ((g ^ (tok&7))<<3));
    bf16x8 w0 = *(const bf16x8*)(wf + ((cb+0)*ksc + ks0+kst)*512 + l*8);
    bf16x8 w1 = *(const bf16x8*)(wf + ((cb+1)*ksc + ks0+kst)*512 + l*8);
    acc[0] = __builtin_amdgcn_mfma_f32_32x32x16_bf16(w0, a, acc[0], 0,0,0);
    acc[1] = __builtin_amdgcn_mfma_f32_32x32x16_bf16(w1, a, acc[1], 0,0,0);
  }
}
// acc + bias -> packed bf16 pairs; channel local index = cbase + cw*32 + 4*hi + 8*q + r
__device__ __forceinline__ void packT32(uint2 (&pk)[2][4], const f32x16 (&acc)[2],
                                        const float* __restrict__ bias, int cbase, int hi, bool relu){
  #pragma unroll
  for (int cw=0;cw<2;cw++)
  #pragma unroll
  for (int q=0;q<4;q++){
    int c0 = cbase + cw*32 + 4*hi + 8*q;
    float v0=acc[cw][q*4+0]+bias[c0],   v1=acc[cw][q*4+1]+bias[c0+1],
          v2=acc[cw][q*4+2]+bias[c0+2], v3=acc[cw][q*4+3]+bias[c0+3];
    if(relu){v0=fmaxf(v0,0.f);v1=fmaxf(v1,0.f);v2=fmaxf(v2,0.f);v3=fmaxf(v3,0.f);}
    pk[cw][q]=(uint2){pk2bf(v0,v1),pk2bf(v2,v3)};
  }
}
__device__ __forceinline__ void store32(u16* dst, const uint2 (&pk)[2][4], int cbase, int tok, int hi){
  #pragma unroll
  for (int cw=0;cw<2;cw++)
  #pragma unroll
  for (int q=0;q<4;q++){
    int c0 = (cbase + cw*32 + 4*hi + 8*q) & 127;
    *(uint2*)&dst[cofs(tok,c0)] = pk[cw][q];
  }
}
// read 16 consecutive channels (c0 multiple of 16) of row t into fp32
__device__ __forceinline__ void load16(const u16* buf, int t, int c0, float* o){
  int g = c0 >> 3;
  union { uint4 v; u16 u[8]; } a, b;
  a.v = *(const uint4*)&buf[(t<<7) + (( g    ^ (t&7))<<3)];
  b.v = *(const uint4*)&buf[(t<<7) + (((g+1) ^ (t&7))<<3)];
  #pragma unroll
  for (int j=0;j<8;j++){ o[j]=b2f(a.u[j]); o[8+j]=b2f(b.u[j]); }
}

// ---------------- fused kernel: 1 block = 64 tokens, 256 threads, 3 blocks/CU ----------------
// arena 45568 B: A(16K) + B(16K) + red(2K) + stats(512) + parf fp32[2560](10K)
// parf: 0 bp |128 g1 |256 be1 |384 g2 |512 be2 |640 Wp[768] |1408 bq |1536 bk |1664 bv |1792 bo |1920 bf2 |2048 bf1[512]
__global__ __launch_bounds__(256,3) void fused(
    const float* __restrict__ x, const float* __restrict__ pol,
    const float* __restrict__ Wp, const u16* __restrict__ ws,
    const float* __restrict__ bp, const float* __restrict__ bq,
    const float* __restrict__ bk, const float* __restrict__ bv,
    const float* __restrict__ bo, const float* __restrict__ bf1,
    const float* __restrict__ bf2, const float* __restrict__ g1,
    const float* __restrict__ be1, const float* __restrict__ g2,
    const float* __restrict__ be2, float* __restrict__ out)
{
  __shared__ __align__(16) unsigned char arena[45568];
  u16*   bufA = (u16*)  (arena);            // xn -> K -> V -> res2(bf16) -> h1 chunks
  u16*   bufB = (u16*)  (arena + 16384);    // xp -> Q -> attended -> hnorm
  float* red   = (float*)(arena + 32768);   // 2048
  float* stats = (float*)(arena + 34816);   // 512
  float* parf  = (float*)(arena + 35328);   // 10240

  const int tid = threadIdx.x;
  const int t   = tid & 63;
  const int p   = __builtin_amdgcn_readfirstlane(tid >> 6);
  const int l   = t;
  const int hi    = l >> 5;
  const int tok   = (p&1)*32 + (l&31);      // token for D^T tiles
  const int cbase = (p>>1)*64;              // local channel base of this wave's 2 ch-tiles
  const int cb2   = (p>>1)*2;               // ch-tile index base (32-wide tiles)

  // ---- params -> fp32 LDS ----
  for (int i=tid; i<2560; i+=256){
    float v;
    if      (i< 128) v = bp [i];
    else if (i< 256) v = g1 [i-128];
    else if (i< 384) v = be1[i-256];
    else if (i< 512) v = g2 [i-384];
    else if (i< 640) v = be2[i-512];
    else if (i<1408) v = Wp [i-640];
    else if (i<1536) v = bq [i-1408];
    else if (i<1664) v = bk [i-1536];
    else if (i<1792) v = bv [i-1664];
    else if (i<1920) v = bo [i-1792];
    else if (i<2048) v = bf2[i-1920];
    else             v = bf1[i-2048];
    parf[i] = v;
  }
  const int bi   = (int)((blockIdx.x*64) >> 17);
  const int dhw0 = (int)((blockIdx.x*64) & (DHW-1));
  const float* xb = x   + (size_t)bi*128*DHW + dhw0;
  const float* pb = pol + (size_t)bi*6*DHW + dhw0;
  float pl6[6];
  #pragma unroll
  for (int j=0;j<6;j++) pl6[j] = pb[(size_t)j*DHW + t];
  __syncthreads();

  // ---- stage: xp = x + polar@Wp + bp (fp32 regs); LN1 sums; xp -> B (bf16) ----
  float xp[32]; float s1=0.f, s2=0.f;
  #pragma unroll
  for (int it=0; it<32; ++it){
    int c = p*32 + it;
    float a = xb[(size_t)c*DHW + t] + parf[c];
    #pragma unroll
    for (int j=0;j<6;j++) a = fmaf(pl6[j], parf[640 + j*128 + c], a);
    xp[it]=a; s1+=a; s2+=a*a;
  }
  #pragma unroll
  for (int cl=0; cl<4; ++cl){
    uint4 pk = (uint4){ pk2bf(xp[cl*8+0],xp[cl*8+1]), pk2bf(xp[cl*8+2],xp[cl*8+3]),
                        pk2bf(xp[cl*8+4],xp[cl*8+5]), pk2bf(xp[cl*8+6],xp[cl*8+7]) };
    *(uint4*)&bufB[(t<<7) + (((p*4+cl) ^ (t&7))<<3)] = pk;
  }
  red[p*64+t]=s1; red[256+p*64+t]=s2;
  __syncthreads();
  if (tid < 64){
    float a=0.f,b=0.f;
    #pragma unroll
    for (int i=0;i<4;i++){ a+=red[i*64+tid]; b+=red[256+i*64+tid]; }
    float m=a*0.0078125f, v=b*0.0078125f-m*m;
    stats[tid*2]=m; stats[tid*2+1]=rsqrtf(v+1e-5f);
  }
  __syncthreads();

  // ---- xn = LN1(xp)*g1+be1 -> A;  residual (bf16 packed) from B at D^T coords ----
  {
    float mn=stats[t*2], rs=stats[t*2+1];
    #pragma unroll
    for (int cl=0; cl<4; ++cl){
      float y[8];
      #pragma unroll
      for (int j=0;j<8;j++){ int c=p*32+cl*8+j; y[j]=(xp[cl*8+j]-mn)*rs*parf[128+c]+parf[256+c]; }
      uint4 pk = (uint4){ pk2bf(y[0],y[1]), pk2bf(y[2],y[3]), pk2bf(y[4],y[5]), pk2bf(y[6],y[7]) };
      *(uint4*)&bufA[(t<<7) + (((p*4+cl) ^ (t&7))<<3)] = pk;
    }
  }
  uint2 resq[2][4];
  #pragma unroll
  for (int cw=0;cw<2;cw++)
  #pragma unroll
  for (int q=0;q<4;q++){
    int c0 = cbase + cw*32 + 4*hi + 8*q;
    resq[cw][q] = *(const uint2*)&bufB[cofs(tok,c0)];
  }
  __syncthreads();

  // ---- QKV:  Q -> B,  V -> regs (packed),  K -> A (after sync) ----
  uint2 pkt[2][4], pkV[2][4];
  {
    f32x16 acc[2];
    acc[0]=z16(); acc[1]=z16();
    mm32(bufA, ws+OFF_WQ, cb2, 8, 0, tok, hi, l, acc);
    packT32(pkt, acc, parf+1408, cbase, hi, false); store32(bufB, pkt, cbase, tok, hi);
    acc[0]=z16(); acc[1]=z16();
    mm32(bufA, ws+OFF_WV, cb2, 8, 0, tok, hi, l, acc);
    packT32(pkV, acc, parf+1664, cbase, hi, false);
    acc[0]=z16(); acc[1]=z16();
    mm32(bufA, ws+OFF_WK, cb2, 8, 0, tok, hi, l, acc);
    __syncthreads();                        // all xn reads done
    packT32(pkt, acc, parf+1536, cbase, hi, false); store32(bufA, pkt, cbase, tok, hi);  // K -> A
  }
  __syncthreads();

  // ---- attention scores + softmax (thread = token t, heads 2p,2p+1) ----
  float sc[16];
  {
    float qv[32];
    load16(bufB, t, p*32, qv); load16(bufB, t, p*32+16, qv+16);
    #pragma unroll
    for (int g8=0; g8<8; ++g8){
      float kv[16]; load16(bufA, t, g8*16, kv);
      float d0=0.f,d1=0.f;
      #pragma unroll
      for (int d=0; d<16; ++d){ d0=fmaf(qv[d],kv[d],d0); d1=fmaf(qv[16+d],kv[d],d1); }
      sc[g8]=d0*0.25f; sc[8+g8]=d1*0.25f;
    }
    #pragma unroll
    for (int hh=0; hh<2; ++hh){
      float mx = sc[hh*8];
      #pragma unroll
      for (int g8=1; g8<8; ++g8) mx = fmaxf(mx, sc[hh*8+g8]);
      float sm=0.f;
      #pragma unroll
      for (int g8=0; g8<8; ++g8){ float e=__expf(sc[hh*8+g8]-mx); sc[hh*8+g8]=e; sm+=e; }
      float inv = 1.f/sm;
      #pragma unroll
      for (int g8=0; g8<8; ++g8) sc[hh*8+g8]*=inv;
    }
  }
  __syncthreads();
  store32(bufA, pkV, cbase, tok, hi);       // V -> A (over K)
  __syncthreads();
  {  // PV; attended -> B (own row/cols, no race)
    float ov[32];
    #pragma unroll
    for (int i=0;i<32;i++) ov[i]=0.f;
    #pragma unroll
    for (int g8=0; g8<8; ++g8){
      float vv[16]; load16(bufA, t, g8*16, vv);
      #pragma unroll
      for (int d=0; d<16; ++d){ ov[d]=fmaf(sc[g8],vv[d],ov[d]); ov[16+d]=fmaf(sc[8+g8],vv[d],ov[16+d]); }
    }
    #pragma unroll
    for (int cl=0; cl<4; ++cl){
      uint4 pk = (uint4){ pk2bf(ov[cl*8+0],ov[cl*8+1]), pk2bf(ov[cl*8+2],ov[cl*8+3]),
                          pk2bf(ov[cl*8+4],ov[cl*8+5]), pk2bf(ov[cl*8+6],ov[cl*8+7]) };
      *(uint4*)&bufB[(t<<7) + (((p*4+cl) ^ (t&7))<<3)] = pk;
    }
  }
  __syncthreads();

  // ---- Wo + residual -> res2 (packed regs) + bf16 copy in A for LN2 ----
  uint2 res2q[2][4];
  {
    f32x16 acc[2];
    acc[0]=z16(); acc[1]=z16();
    mm32(bufB, ws+OFF_WO, cb2, 8, 0, tok, hi, l, acc);
    #pragma unroll
    for (int cw=0;cw<2;cw++)
    #pragma unroll
    for (int q=0;q<4;q++){
      int c0 = cbase + cw*32 + 4*hi + 8*q;
      uint2 r = resq[cw][q];
      float v0 = acc[cw][q*4+0]+parf[1792+c0]  +lo2f(r.x);
      float v1 = acc[cw][q*4+1]+parf[1793+c0]  +hi2f(r.x);
      float v2 = acc[cw][q*4+2]+parf[1794+c0]  +lo2f(r.y);
      float v3 = acc[cw][q*4+3]+parf[1795+c0]  +hi2f(r.y);
      uint2 pk = (uint2){ pk2bf(v0,v1), pk2bf(v2,v3) };
      res2q[cw][q] = pk;
      *(uint2*)&bufA[cofs(tok,c0)] = pk;
    }
  }
  __syncthreads();

  // ---- LN2 ----
  float ovl[32]; s1=0.f; s2=0.f;
  #pragma unroll
  for (int cl=0; cl<4; ++cl){
    union { uint4 v; u16 u[8]; } pk;
    pk.v = *(const uint4*)&bufA[(t<<7) + (((p*4+cl) ^ (t&7))<<3)];
    #pragma unroll
    for (int j=0;j<8;j++){ float v=b2f(pk.u[j]); ovl[cl*8+j]=v; s1+=v; s2+=v*v; }
  }
  red[p*64+t]=s1; red[256+p*64+t]=s2;
  __syncthreads();
  if (tid < 64){
    float a=0.f,b=0.f;
    #pragma unroll
    for (int i=0;i<4;i++){ a+=red[i*64+tid]; b+=red[256+i*64+tid]; }
    float m=a*0.0078125f, v=b*0.0078125f-m*m;
    stats[tid*2]=m; stats[tid*2+1]=rsqrtf(v+1e-5f);
  }
  __syncthreads();
  {
    float mn=stats[t*2], rs=stats[t*2+1];
    #pragma unroll
    for (int cl=0; cl<4; ++cl){
      float y[8];
      #pragma unroll
      for (int j=0;j<8;j++){ int c=p*32+cl*8+j; y[j]=(ovl[cl*8+j]-mn)*rs*parf[384+c]+parf[512+c]; }
      uint4 pk = (uint4){ pk2bf(y[0],y[1]), pk2bf(y[2],y[3]), pk2bf(y[4],y[5]), pk2bf(y[6],y[7]) };
      *(uint4*)&bufB[(t<<7) + (((p*4+cl) ^ (t&7))<<3)] = pk;   // hnorm -> B
    }
  }
  __syncthreads();

  // ---- FFN: 4 chunks of 128 cols; h1 chunk -> A; FFN2 accumulates in regs ----
  f32x16 acc2[2]; acc2[0]=z16(); acc2[1]=z16();
  #pragma unroll 1
  for (int ch=0; ch<4; ++ch){
    f32x16 acc1[2]; acc1[0]=z16(); acc1[1]=z16();
    mm32(bufB, ws+OFF_W1, ch*4+cb2, 8, 0, tok, hi, l, acc1);
    packT32(pkt, acc1, parf+2048+ch*128, cbase, hi, true); store32(bufA, pkt, cbase, tok, hi);
    __syncthreads();
    mm32(bufA, ws+OFF_W2, cb2, 32, ch*8, tok, hi, l, acc2);
    __syncthreads();
  }

  // ---- final: + bf2 + res2, direct coalesced stores (128B-contiguous segments) ----
  float* ob = out + (size_t)bi*128*DHW + dhw0;
  #pragma unroll
  for (int cw=0;cw<2;cw++)
  #pragma unroll
  for (int q=0;q<4;q++){
    int c0 = cbase + cw*32 + 4*hi + 8*q;
    uint2 r = res2q[cw][q];
    ob[(size_t)(c0+0)*DHW + tok] = acc2[cw][q*4+0] + parf[1920+c0]   + lo2f(r.x);
    ob[(size_t)(c0+1)*DHW + tok] = acc2[cw][q*4+1] + parf[1921+c0]   + hi2f(r.x);
    ob[(size_t)(c0+2)*DHW + tok] = acc2[cw][q*4+2] + parf[1922+c0]   + lo2f(r.y);
    ob[(size_t)(c0+3)*DHW + tok] = acc2[cw][q*4+3] + parf[1923+c0]   + hi2f(r.y);
  }
}

extern "C" void kernel_launch(void* const* d_in, const int* in_sizes, int n_in,
                              void* d_out, int out_size, void* d_ws, size_t ws_size,
                              hipStream_t stream){
  const float* x   = (const float*)d_in[0];
  const float* pol = (const float*)d_in[1];
  const float* Wq  = (const float*)d_in[2];
  const float* bq  = (const float*)d_in[3];
  const float* Wk  = (const float*)d_in[4];
  const float* bk  = (const float*)d_in[5];
  const float* Wv  = (const float*)d_in[6];
  const float* bv  = (const float*)d_in[7];
  const float* Wp  = (const float*)d_in[8];
  const float* bp  = (const float*)d_in[9];
  const float* Wo  = (const float*)d_in[10];
  const float* bo  = (const float*)d_in[11];
  const float* g1  = (const float*)d_in[12];
  const float* be1 = (const float*)d_in[13];
  const float* g2  = (const float*)d_in[14];
  const float* be2 = (const float*)d_in[15];
  const float* W1  = (const float*)d_in[16];
  const float* bf1 = (const float*)d_in[17];
  const float* W2  = (const float*)d_in[18];
  const float* bf2 = (const float*)d_in[19];
  u16* ws = (u16*)d_ws;   // needs 384 KB
  pack_w<<<96, 256, 0, stream>>>(Wq, Wk, Wv, Wo, W1, W2, ws);
  fused<<<4096, 256, 0, stream>>>(x, pol, Wp, ws, bp, bq, bk, bv, bo, bf1, bf2,
                                  g1, be1, g2, be2, (float*)d_out);
}